// Round 8
// baseline (267.658 us; speedup 1.0000x reference)
//
#include <hip/hip_runtime.h>
#include <hip/hip_bf16.h>

using bf16 = __hip_bfloat16;
typedef __attribute__((ext_vector_type(8))) short short8;
typedef __attribute__((ext_vector_type(4))) float floatx4;

#define DEVINL __device__ __forceinline__

constexpr int NHEAD = 16;
constexpr int DH = 64;
constexpr int T_ = 2048;
constexpr int DM = 1024;
constexpr float LOG2E = 1.44269504088896340736f;

typedef const __attribute__((address_space(1))) unsigned int* gas1_t;
typedef __attribute__((address_space(3))) unsigned int* las3_t;

DEVINL void async_cp16(void* lds, const void* g) {
  __builtin_amdgcn_global_load_lds((gas1_t)g, (las3_t)lds, 16, 0, 0);
}

// Per-wave drain of outstanding global_load_lds DMAs. [verified R5]
DEVINL void wave_wait_dma() {
  __builtin_amdgcn_s_waitcnt(0x0F70);  // vmcnt(0); expcnt/lgkmcnt ignored
  __builtin_amdgcn_sched_barrier(0);
}

// Drain this wave's LDS reads so a following DMA may overwrite the buffer.
DEVINL void wave_wait_lds_reads() {
  __builtin_amdgcn_sched_barrier(0);
  __builtin_amdgcn_s_waitcnt(0xC07F);  // lgkmcnt(0); vmcnt/expcnt ignored
  __builtin_amdgcn_sched_barrier(0);
}

struct alignas(8) bf4 { bf16 x, y, z, w; };

DEVINL unsigned pack2(float a, float b) {
  union { bf16 h[2]; unsigned u; } x;
  x.h[0] = __float2bfloat16(a);
  x.h[1] = __float2bfloat16(b);
  return x.u;
}

// ---------------------------------------------------------------- convert
struct CvtArgs { const float* src[7]; bf16* dst[7]; };

__global__ __launch_bounds__(256) void cvt_kernel(CvtArgs a) {
  const int total = 3 * 1048576 + 4 * 262144;
  for (int i = blockIdx.x * 256 + threadIdx.x; i < total; i += gridDim.x * 256) {
    int t, off;
    if (i < 3 * 1048576) { t = i >> 20; off = i & 1048575; }
    else { int j = i - 3 * 1048576; t = 3 + (j >> 18); off = j & 262143; }
    float4 v = ((const float4*)a.src[t])[off];
    bf4 o;
    o.x = __float2bfloat16(v.x); o.y = __float2bfloat16(v.y);
    o.z = __float2bfloat16(v.z); o.w = __float2bfloat16(v.w);
    ((bf4*)a.dst[t])[off] = o;
  }
}

// ---------------------------------------------------------------- GEMM (C = A @ W^T + bias)
// R8: BK=64 (half the barrier count of R7's BK=32). BM=128; BN = JT*32.
// 64-wide rows = 8 chunks of 16B, XOR-swizzled: slot = chunk ^ (row&7).
template <int EPI, int JT>
DEVINL void gemm_body(const bf16* __restrict__ A, const bf16* __restrict__ W,
                      const float* __restrict__ bias, void* __restrict__ out,
                      float scale, int vmode, int row0, int col0) {
  constexpr int K = 1024;
  constexpr int BN = JT * 32;
  __shared__ bf16 As[128 * 64];
  __shared__ bf16 Bs[BN * 64];
  const int tid = threadIdx.x;
  const int lane = tid & 63, l16 = lane & 15, quad = lane >> 4;
  const int wave = tid >> 6;
  const int wm = (wave & 1) << 6, wn = (wave >> 1) * (JT * 16);

  floatx4 acc[4][JT];
#pragma unroll
  for (int i = 0; i < 4; ++i)
#pragma unroll
    for (int j = 0; j < JT; ++j) acc[i][j] = (floatx4){0.f, 0.f, 0.f, 0.f};

  for (int kt = 0; kt < K / 64; ++kt) {
    const int k0 = kt * 64;
#pragma unroll
    for (int s = 0; s < 4; ++s) {          // A: 128 rows x 8 chunks
      int t = tid + s * 256;
      int r = t >> 3, c = (t & 7) ^ (r & 7);
      async_cp16(As + t * 8, A + (size_t)(row0 + r) * K + k0 + c * 8);
    }
#pragma unroll
    for (int s = 0; s < JT; ++s) {         // B: BN rows x 8 chunks
      int t = tid + s * 256;
      int r = t >> 3, c = (t & 7) ^ (r & 7);
      async_cp16(Bs + t * 8, W + (size_t)(col0 + r) * K + k0 + c * 8);
    }
    __syncthreads();
    short8 af[4][2], bfr[JT][2];
#pragma unroll
    for (int kk = 0; kk < 2; ++kk) {
#pragma unroll
      for (int i = 0; i < 4; ++i) {
        int r = wm + i * 16 + l16;
        int cg = kk * 4 + quad;
        af[i][kk] = *(const short8*)(As + (r * 8 + (cg ^ (r & 7))) * 8);
      }
#pragma unroll
      for (int j = 0; j < JT; ++j) {
        int r = wn + j * 16 + l16;
        int cg = kk * 4 + quad;
        bfr[j][kk] = *(const short8*)(Bs + (r * 8 + (cg ^ (r & 7))) * 8);
      }
    }
#pragma unroll
    for (int kk = 0; kk < 2; ++kk)
#pragma unroll
      for (int i = 0; i < 4; ++i)
#pragma unroll
        for (int j = 0; j < JT; ++j)
          acc[i][j] = __builtin_amdgcn_mfma_f32_16x16x32_bf16(af[i][kk], bfr[j][kk],
                                                              acc[i][j], 0, 0, 0);
    __syncthreads();
  }

  // C/D layout: col = lane&15, row = quad*4 + reg  [m89/m91]
#pragma unroll
  for (int j = 0; j < JT; ++j) {
    const int col = col0 + wn + j * 16 + l16;
    const float bv = bias[col];
#pragma unroll
    for (int i = 0; i < 4; ++i) {
      const int m0 = row0 + wm + i * 16 + quad * 4;
      if (EPI == 1) {
#pragma unroll
        for (int r = 0; r < 4; ++r)
          ((float*)out)[(size_t)(m0 + r) * DM + col] = acc[i][j][r] + bv;
      } else if (vmode) {
        const int b = m0 >> 11, t = m0 & 2047, h = col >> 6, d = col & 63;
        bf4 o;
        o.x = __float2bfloat16((acc[i][j][0] + bv) * scale);
        o.y = __float2bfloat16((acc[i][j][1] + bv) * scale);
        o.z = __float2bfloat16((acc[i][j][2] + bv) * scale);
        o.w = __float2bfloat16((acc[i][j][3] + bv) * scale);
        *(bf4*)((bf16*)out + (((size_t)(b * NHEAD + h)) * DH + d) * T_ + t) = o;
      } else {
#pragma unroll
        for (int r = 0; r < 4; ++r) {
          const int m = m0 + r;
          const int b = m >> 11, t = m & 2047, h = col >> 6, d = col & 63;
          ((bf16*)out)[(((size_t)(b * NHEAD + h)) * T_ + t) * DH + d] =
              __float2bfloat16((acc[i][j][r] + bv) * scale);
        }
      }
    }
  }
}

struct GemmBatch {
  const bf16* A[3]; const bf16* W[3]; const float* bias[3];
  bf16* out[3]; float scale[3]; int vmode[3];
};

// XCD-aware swizzle (XCD = linear_block_id % 8) [verified R7]: the 8 col-blocks
// sharing an A row-block land on ONE XCD. 768 blocks @3/CU = fully resident.
__global__ __launch_bounds__(256, 3) void qkv_gemm(GemmBatch p) {
  const int n = blockIdx.x;          // 0..767
  const int g = n >> 8;              // matrix
  const int m = n & 255;
  const int r = ((m >> 6) << 3) | (m & 7);  // row-block 0..31
  const int c = (m >> 3) & 7;               // col-block 0..7
  gemm_body<0, 4>(p.A[g], p.W[g], p.bias[g], p.out[g], p.scale[g], p.vmode[g],
                  r * 128, c * 128);
}

__global__ __launch_bounds__(256, 2) void out_gemm(const bf16* __restrict__ A,
                                                   const bf16* __restrict__ W,
                                                   const float* __restrict__ bias,
                                                   float* __restrict__ out) {
  const int n = blockIdx.x;          // 0..511
  const int r = ((n >> 7) << 3) | (n & 7);  // row-block 0..31
  const int c = (n >> 3) & 15;              // col-block 0..15
  gemm_body<1, 2>(A, W, bias, out, 1.0f, 0, r * 128, c * 64);
}

// ---------------------------------------------------------------- flash attention
// S^T form, no-max softmax, barrier-free K-loop, XCD swizzle [R5-R7].
// R8: single-buffered per-wave K/V tiles (8 KB/wave, LDS 33 KB): frags are in
// registers after the lgkmcnt(0) drain, so the same buffer takes the next
// prefetch -- same 1-iteration prefetch distance, half the LDS. launch_bounds
// (256,3) -> 12 waves/CU. Combine runs in 2 rounds (8 KB publish buffer).
__global__ __launch_bounds__(256, 3)
void attn_kernel(const bf16* __restrict__ Q, const bf16* __restrict__ Kg_,
                 const bf16* __restrict__ Vt, bf16* __restrict__ Og) {
  const int n = blockIdx.x;                   // 0..511
  const int bh = ((n >> 7) << 3) | (n & 7);   // 0..31, == n mod 8
  const int qp = (n >> 3) & 15;               // 0..15
  const int tid = threadIdx.x, lane = tid & 63, wave = tid >> 6;
  const int quad = lane >> 4, l16 = lane & 15;

  // per-wave [ K 32x64 : 0..2047 | V^T 64x32 : 2048..4095 ]
  __shared__ bf16 tiles[4][4096];
  __shared__ float lx[4][64];

  const bf16* Kp = Kg_ + (size_t)bh * T_ * DH;
  const bf16* Vp = Vt + (size_t)bh * DH * T_;
  const bf16* Qbase = Q + (size_t)bh * T_ * DH;
  const int b = bh >> 4, h = bh & 15;

#pragma unroll
  for (int phase = 0; phase < 2; ++phase) {
    const int qt = phase ? (31 - qp) : qp;
    const int q0 = qt * 64;
    const int ntiles = 2 * (qt + 1);
    const bf16* Qp = Qbase + (size_t)q0 * DH;

    // Q B-frags for all 64 q of this tile: lane n=l16 -> q, k = kk*32+quad*8+j
    short8 qf[4][2];
#pragma unroll
    for (int qi = 0; qi < 4; ++qi)
#pragma unroll
      for (int kk = 0; kk < 2; ++kk)
        qf[qi][kk] = *(const short8*)(Qp + (size_t)(qi * 16 + l16) * DH + kk * 32 + quad * 8);

    floatx4 Oa[4][4];
    float l_r[4];
#pragma unroll
    for (int qi = 0; qi < 4; ++qi) {
#pragma unroll
      for (int td = 0; td < 4; ++td) Oa[qi][td] = (floatx4){0.f, 0.f, 0.f, 0.f};
      l_r[qi] = 0.f;
    }

    // prime: this wave's first tile
    if (wave < ntiles) {
#pragma unroll
      for (int i = 0; i < 4; ++i) {
        int t = lane + i * 64;
        int rk = t >> 3, ck = (t & 7) ^ (rk & 7);
        async_cp16(&tiles[wave][t * 8], Kp + (size_t)(wave * 32 + rk) * DH + ck * 8);
        int rv = t >> 2, cv = (t & 3) ^ (rv & 3);
        async_cp16(&tiles[wave][2048 + t * 8], Vp + (size_t)rv * T_ + wave * 32 + cv * 8);
      }
    }

    for (int kt2 = wave; kt2 < ntiles; kt2 += 4) {
      const bf16* Ks = &tiles[wave][0];
      const bf16* Vs = &tiles[wave][2048];

      wave_wait_dma();   // DMA data landed
      short8 kf[2][2], vf[4];
#pragma unroll
      for (int kk = 0; kk < 2; ++kk)
#pragma unroll
        for (int tj = 0; tj < 2; ++tj) {
          int r = tj * 16 + l16;
          int cg = kk * 4 + quad;
          kf[kk][tj] = *(const short8*)(Ks + (r * 8 + (cg ^ (r & 7))) * 8);
        }
#pragma unroll
      for (int td = 0; td < 4; ++td) {
        int r = td * 16 + l16;
        vf[td] = *(const short8*)(Vs + (r * 4 + (quad ^ (r & 3))) * 8);
      }
      wave_wait_lds_reads();  // frags in regs; buffer may be overwritten

      // prefetch this wave's next tile (kt2+4) into the SAME buffer
      if (kt2 + 4 < ntiles) {
#pragma unroll
        for (int i = 0; i < 4; ++i) {
          int t = lane + i * 64;
          int rk = t >> 3, ck = (t & 7) ^ (rk & 7);
          async_cp16(&tiles[wave][t * 8],
                     Kp + (size_t)((kt2 + 4) * 32 + rk) * DH + ck * 8);
          int rv = t >> 2, cv = (t & 3) ^ (rv & 3);
          async_cp16(&tiles[wave][2048 + t * 8],
                     Vp + (size_t)rv * T_ + (kt2 + 4) * 32 + cv * 8);
        }
      }

      // S^T[key][q]: C layout row=key=quad*4+reg (+16*tj), col=q=l16
      floatx4 S[4][2];
#pragma unroll
      for (int qi = 0; qi < 4; ++qi)
#pragma unroll
        for (int tj = 0; tj < 2; ++tj) S[qi][tj] = (floatx4){0.f, 0.f, 0.f, 0.f};
#pragma unroll
      for (int kk = 0; kk < 2; ++kk)
#pragma unroll
        for (int tj = 0; tj < 2; ++tj)
#pragma unroll
          for (int qi = 0; qi < 4; ++qi)
            S[qi][tj] = __builtin_amdgcn_mfma_f32_16x16x32_bf16(kf[kk][tj], qf[qi][kk],
                                                                S[qi][tj], 0, 0, 0);

      if (kt2 >= 2 * qt) {  // diagonal tiles: causal mask (key > q)
#pragma unroll
        for (int qi = 0; qi < 4; ++qi) {
          const int q = q0 + qi * 16 + l16;
#pragma unroll
          for (int tj = 0; tj < 2; ++tj)
#pragma unroll
            for (int r = 0; r < 4; ++r) {
              int key = kt2 * 32 + tj * 16 + quad * 4 + r;
              if (key > q) S[qi][tj][r] = -3.0e38f;
            }
        }
      }

      // no-max softmax: exp2 (scale*log2e folded into Q), per-lane partial l
      unsigned lo[4][2], hi[4][2];
#pragma unroll
      for (int qi = 0; qi < 4; ++qi) {
#pragma unroll
        for (int tj = 0; tj < 2; ++tj)
#pragma unroll
          for (int r = 0; r < 4; ++r)
            S[qi][tj][r] = __builtin_amdgcn_exp2f(S[qi][tj][r]);
        l_r[qi] += ((S[qi][0][0] + S[qi][0][1]) + (S[qi][0][2] + S[qi][0][3])) +
                   ((S[qi][1][0] + S[qi][1][1]) + (S[qi][1][2] + S[qi][1][3]));
#pragma unroll
        for (int tj = 0; tj < 2; ++tj) {
          lo[qi][tj] = pack2(S[qi][tj][0], S[qi][tj][1]);
          hi[qi][tj] = pack2(S[qi][tj][2], S[qi][tj][3]);
        }
      }

      // P^T B-frag (32 keys) via quad permute [verified R2/R3/R5], then PV
      const int sl0 = l16 + ((lane & 16) << 1);
      const int sl1 = sl0 + 16;
      const bool sel = (quad >> 1) != 0;
#pragma unroll
      for (int qi = 0; qi < 4; ++qi) {
        unsigned a0 = __shfl((int)lo[qi][0], sl0), b0 = __shfl((int)lo[qi][1], sl0);
        unsigned a1 = __shfl((int)hi[qi][0], sl0), b1 = __shfl((int)hi[qi][1], sl0);
        unsigned a2 = __shfl((int)lo[qi][0], sl1), b2 = __shfl((int)lo[qi][1], sl1);
        unsigned a3 = __shfl((int)hi[qi][0], sl1), b3 = __shfl((int)hi[qi][1], sl1);
        union { unsigned u[4]; short8 v; } pfu;
        pfu.u[0] = sel ? b0 : a0;
        pfu.u[1] = sel ? b1 : a1;
        pfu.u[2] = sel ? b2 : a2;
        pfu.u[3] = sel ? b3 : a3;
#pragma unroll
        for (int td = 0; td < 4; ++td)
          Oa[qi][td] = __builtin_amdgcn_mfma_f32_16x16x32_bf16(vf[td], pfu.v, Oa[qi][td], 0, 0, 0);
      }
    }

    // wave-level l: sum across quads
#pragma unroll
    for (int qi = 0; qi < 4; ++qi) {
      l_r[qi] += __shfl_xor(l_r[qi], 16);
      l_r[qi] += __shfl_xor(l_r[qi], 32);
    }

    // 2-round combine through the (drained) 8 KB per-wave regions.
#pragma unroll
    for (int round = 0; round < 2; ++round) {
      float* cb = (float*)&tiles[wave][0];
#pragma unroll
      for (int qi2 = 0; qi2 < 2; ++qi2)
#pragma unroll
        for (int td = 0; td < 4; ++td)
          ((floatx4*)cb)[(qi2 * 4 + td) * 64 + lane] = Oa[round * 2 + qi2][td];
      if (round == 0 && quad == 0) {
#pragma unroll
        for (int qi = 0; qi < 4; ++qi) lx[wave][qi * 16 + l16] = l_r[qi];
      }
      __syncthreads();
      {
        const int qi_g = round * 2 + (wave >> 1);
        const int qi2 = wave >> 1;
        const float lsum = lx[0][qi_g * 16 + l16] + lx[1][qi_g * 16 + l16] +
                           lx[2][qi_g * 16 + l16] + lx[3][qi_g * 16 + l16];
        const float rl = __builtin_amdgcn_rcpf(lsum);
        bf16* op = Og + ((size_t)(b * T_ + q0 + qi_g * 16 + l16)) * DM + h * DH + quad * 4;
#pragma unroll
        for (int u = 0; u < 2; ++u) {
          const int td = (wave & 1) * 2 + u;
          floatx4 s = (floatx4){0.f, 0.f, 0.f, 0.f};
#pragma unroll
          for (int src = 0; src < 4; ++src) {
            floatx4 p = ((const floatx4*)&tiles[src][0])[(qi2 * 4 + td) * 64 + lane];
            s[0] += p[0]; s[1] += p[1]; s[2] += p[2]; s[3] += p[3];
          }
          bf4 o;
          o.x = __float2bfloat16(s[0] * rl);
          o.y = __float2bfloat16(s[1] * rl);
          o.z = __float2bfloat16(s[2] * rl);
          o.w = __float2bfloat16(s[3] * rl);
          *(bf4*)(op + td * 16) = o;
        }
      }
      __syncthreads();  // protect regions before next publish / next phase
    }
  }
}

// ---------------------------------------------------------------- launch
extern "C" void kernel_launch(void* const* d_in, const int* in_sizes, int n_in,
                              void* d_out, int out_size, void* d_ws, size_t ws_size,
                              hipStream_t stream) {
  (void)in_sizes; (void)n_in; (void)out_size; (void)ws_size;
  const float* query = (const float*)d_in[0];
  const float* key_  = (const float*)d_in[1];
  const float* value = (const float*)d_in[2];
  const float* q_w = (const float*)d_in[3];
  const float* q_b = (const float*)d_in[4];
  const float* k_w = (const float*)d_in[5];
  const float* k_b = (const float*)d_in[6];
  const float* v_w = (const float*)d_in[7];
  const float* v_b = (const float*)d_in[8];
  const float* o_w = (const float*)d_in[9];
  const float* o_b = (const float*)d_in[10];

  char* ws = (char*)d_ws;
  const size_t MB = (size_t)1 << 20;
  bf16* Xq = (bf16*)(ws + 0 * MB);
  bf16* Xk = (bf16*)(ws + 8 * MB);
  bf16* Xv = (bf16*)(ws + 16 * MB);
  bf16* Wq = (bf16*)(ws + 24 * MB);
  bf16* Wk = (bf16*)(ws + 26 * MB);
  bf16* Wv = (bf16*)(ws + 28 * MB);
  bf16* Wo = (bf16*)(ws + 30 * MB);
  bf16* Qb = (bf16*)(ws + 32 * MB);  // [B,H,T,dh]
  bf16* Kb = (bf16*)(ws + 40 * MB);  // [B,H,T,dh]
  bf16* Vt = (bf16*)(ws + 48 * MB);  // [B,H,dh,T]
  bf16* An = (bf16*)(ws + 64 * MB);  // [B,T,D]

  CvtArgs ca;
  ca.src[0] = query; ca.src[1] = key_; ca.src[2] = value;
  ca.src[3] = q_w; ca.src[4] = k_w; ca.src[5] = v_w; ca.src[6] = o_w;
  ca.dst[0] = Xq; ca.dst[1] = Xk; ca.dst[2] = Xv;
  ca.dst[3] = Wq; ca.dst[4] = Wk; ca.dst[5] = Wv; ca.dst[6] = Wo;
  cvt_kernel<<<2048, 256, 0, stream>>>(ca);

  GemmBatch gb;
  gb.A[0] = Xq; gb.A[1] = Xk; gb.A[2] = Xv;
  gb.W[0] = Wq; gb.W[1] = Wk; gb.W[2] = Wv;
  gb.bias[0] = q_b; gb.bias[1] = k_b; gb.bias[2] = v_b;
  gb.out[0] = Qb; gb.out[1] = Kb; gb.out[2] = Vt;
  gb.scale[0] = 0.125f * LOG2E; gb.scale[1] = 1.f; gb.scale[2] = 1.f;
  gb.vmode[0] = 0; gb.vmode[1] = 0; gb.vmode[2] = 1;
  qkv_gemm<<<768, 256, 0, stream>>>(gb);

  attn_kernel<<<512, 256, 0, stream>>>(Qb, Kb, Vt, An);
  out_gemm<<<512, 256, 0, stream>>>(An, Wo, o_b, (float*)d_out);
}

// Round 9
// 203.998 us; speedup vs baseline: 1.3121x; 1.3121x over previous
//
#include <hip/hip_runtime.h>
#include <hip/hip_bf16.h>

using bf16 = __hip_bfloat16;
typedef __attribute__((ext_vector_type(8))) short short8;
typedef __attribute__((ext_vector_type(4))) float floatx4;

#define DEVINL __device__ __forceinline__

constexpr int NHEAD = 16;
constexpr int DH = 64;
constexpr int T_ = 2048;
constexpr int DM = 1024;
constexpr float LOG2E = 1.44269504088896340736f;

typedef const __attribute__((address_space(1))) unsigned int* gas1_t;
typedef __attribute__((address_space(3))) unsigned int* las3_t;

DEVINL void async_cp16(void* lds, const void* g) {
  __builtin_amdgcn_global_load_lds((gas1_t)g, (las3_t)lds, 16, 0, 0);
}

// Per-wave drain of outstanding global_load_lds DMAs. [verified R5]
DEVINL void wave_wait_dma() {
  __builtin_amdgcn_s_waitcnt(0x0F70);  // vmcnt(0)
  __builtin_amdgcn_sched_barrier(0);
}

struct alignas(8) bf4 { bf16 x, y, z, w; };

DEVINL unsigned pack2(float a, float b) {
  union { bf16 h[2]; unsigned u; } x;
  x.h[0] = __float2bfloat16(a);
  x.h[1] = __float2bfloat16(b);
  return x.u;
}

// ---------------------------------------------------------------- convert
struct CvtArgs { const float* src[7]; bf16* dst[7]; };

__global__ __launch_bounds__(256) void cvt_kernel(CvtArgs a) {
  const int total = 3 * 1048576 + 4 * 262144;
  for (int i = blockIdx.x * 256 + threadIdx.x; i < total; i += gridDim.x * 256) {
    int t, off;
    if (i < 3 * 1048576) { t = i >> 20; off = i & 1048575; }
    else { int j = i - 3 * 1048576; t = 3 + (j >> 18); off = j & 262143; }
    float4 v = ((const float4*)a.src[t])[off];
    bf4 o;
    o.x = __float2bfloat16(v.x); o.y = __float2bfloat16(v.y);
    o.z = __float2bfloat16(v.z); o.w = __float2bfloat16(v.w);
    ((bf4*)a.dst[t])[off] = o;
  }
}

// ---------------------------------------------------------------- GEMM (C = A @ W^T + bias)
// BK=64 [R8]: half the barrier count of BK=32. BM=128; BN = JT*32.
// 64-wide rows = 8 chunks of 16B, XOR-swizzled: slot = chunk ^ (row&7).
template <int EPI, int JT>
DEVINL void gemm_body(const bf16* __restrict__ A, const bf16* __restrict__ W,
                      const float* __restrict__ bias, void* __restrict__ out,
                      float scale, int vmode, int row0, int col0) {
  constexpr int K = 1024;
  constexpr int BN = JT * 32;
  __shared__ bf16 As[128 * 64];
  __shared__ bf16 Bs[BN * 64];
  const int tid = threadIdx.x;
  const int lane = tid & 63, l16 = lane & 15, quad = lane >> 4;
  const int wave = tid >> 6;
  const int wm = (wave & 1) << 6, wn = (wave >> 1) * (JT * 16);

  floatx4 acc[4][JT];
#pragma unroll
  for (int i = 0; i < 4; ++i)
#pragma unroll
    for (int j = 0; j < JT; ++j) acc[i][j] = (floatx4){0.f, 0.f, 0.f, 0.f};

  for (int kt = 0; kt < K / 64; ++kt) {
    const int k0 = kt * 64;
#pragma unroll
    for (int s = 0; s < 4; ++s) {          // A: 128 rows x 8 chunks
      int t = tid + s * 256;
      int r = t >> 3, c = (t & 7) ^ (r & 7);
      async_cp16(As + t * 8, A + (size_t)(row0 + r) * K + k0 + c * 8);
    }
#pragma unroll
    for (int s = 0; s < JT; ++s) {         // B: BN rows x 8 chunks
      int t = tid + s * 256;
      int r = t >> 3, c = (t & 7) ^ (r & 7);
      async_cp16(Bs + t * 8, W + (size_t)(col0 + r) * K + k0 + c * 8);
    }
    __syncthreads();
    short8 af[4][2], bfr[JT][2];
#pragma unroll
    for (int kk = 0; kk < 2; ++kk) {
#pragma unroll
      for (int i = 0; i < 4; ++i) {
        int r = wm + i * 16 + l16;
        int cg = kk * 4 + quad;
        af[i][kk] = *(const short8*)(As + (r * 8 + (cg ^ (r & 7))) * 8);
      }
#pragma unroll
      for (int j = 0; j < JT; ++j) {
        int r = wn + j * 16 + l16;
        int cg = kk * 4 + quad;
        bfr[j][kk] = *(const short8*)(Bs + (r * 8 + (cg ^ (r & 7))) * 8);
      }
    }
#pragma unroll
    for (int kk = 0; kk < 2; ++kk)
#pragma unroll
      for (int i = 0; i < 4; ++i)
#pragma unroll
        for (int j = 0; j < JT; ++j)
          acc[i][j] = __builtin_amdgcn_mfma_f32_16x16x32_bf16(af[i][kk], bfr[j][kk],
                                                              acc[i][j], 0, 0, 0);
    __syncthreads();
  }

  // C/D layout: col = lane&15, row = quad*4 + reg  [m89/m91]
#pragma unroll
  for (int j = 0; j < JT; ++j) {
    const int col = col0 + wn + j * 16 + l16;
    const float bv = bias[col];
#pragma unroll
    for (int i = 0; i < 4; ++i) {
      const int m0 = row0 + wm + i * 16 + quad * 4;
      if (EPI == 1) {
#pragma unroll
        for (int r = 0; r < 4; ++r)
          ((float*)out)[(size_t)(m0 + r) * DM + col] = acc[i][j][r] + bv;
      } else if (vmode) {
        const int b = m0 >> 11, t = m0 & 2047, h = col >> 6, d = col & 63;
        bf4 o;
        o.x = __float2bfloat16((acc[i][j][0] + bv) * scale);
        o.y = __float2bfloat16((acc[i][j][1] + bv) * scale);
        o.z = __float2bfloat16((acc[i][j][2] + bv) * scale);
        o.w = __float2bfloat16((acc[i][j][3] + bv) * scale);
        *(bf4*)((bf16*)out + (((size_t)(b * NHEAD + h)) * DH + d) * T_ + t) = o;
      } else {
#pragma unroll
        for (int r = 0; r < 4; ++r) {
          const int m = m0 + r;
          const int b = m >> 11, t = m & 2047, h = col >> 6, d = col & 63;
          ((bf16*)out)[(((size_t)(b * NHEAD + h)) * T_ + t) * DH + d] =
              __float2bfloat16((acc[i][j][r] + bv) * scale);
        }
      }
    }
  }
}

struct GemmBatch {
  const bf16* A[3]; const bf16* W[3]; const float* bias[3];
  bf16* out[3]; float scale[3]; int vmode[3];
};

// XCD-aware swizzle (XCD = linear_block_id % 8) [verified R7]: the 8 col-blocks
// sharing an A row-block land on ONE XCD. 768 blocks @3/CU = fully resident.
__global__ __launch_bounds__(256, 3) void qkv_gemm(GemmBatch p) {
  const int n = blockIdx.x;          // 0..767
  const int g = n >> 8;              // matrix
  const int m = n & 255;
  const int r = ((m >> 6) << 3) | (m & 7);  // row-block 0..31
  const int c = (m >> 3) & 7;               // col-block 0..7
  gemm_body<0, 4>(p.A[g], p.W[g], p.bias[g], p.out[g], p.scale[g], p.vmode[g],
                  r * 128, c * 128);
}

__global__ __launch_bounds__(256, 2) void out_gemm(const bf16* __restrict__ A,
                                                   const bf16* __restrict__ W,
                                                   const float* __restrict__ bias,
                                                   float* __restrict__ out) {
  const int n = blockIdx.x;          // 0..511
  const int r = ((n >> 7) << 3) | (n & 7);  // row-block 0..31
  const int c = (n >> 3) & 15;              // col-block 0..15
  gemm_body<1, 2>(A, W, bias, out, 1.0f, 0, r * 128, c * 64);
}

// ---------------------------------------------------------------- flash attention
// R7 version verbatim (verified 41.6 us, VGPR 116, no spill). S^T form, no-max
// softmax, barrier-free K-loop, 4 balanced waves, per-wave double-buffered
// tiles, XCD swizzle. launch_bounds(256,2): do NOT raise -- (256,3) spills
// ~200 MB of scratch (R8 post-mortem).
__global__ __launch_bounds__(256, 2)
void attn_kernel(const bf16* __restrict__ Q, const bf16* __restrict__ Kg_,
                 const bf16* __restrict__ Vt, bf16* __restrict__ Og) {
  const int n = blockIdx.x;                   // 0..511
  const int bh = ((n >> 7) << 3) | (n & 7);   // 0..31, == n mod 8
  const int qp = (n >> 3) & 15;               // 0..15
  const int tid = threadIdx.x, lane = tid & 63, wave = tid >> 6;
  const int quad = lane >> 4, l16 = lane & 15;

  // per-wave double-buffered [ K 32x64 : 0..2047 | V^T 64x32 : 2048..4095 ]
  __shared__ bf16 tiles[4][2][4096];
  __shared__ float lx[4][64];

  const bf16* Kp = Kg_ + (size_t)bh * T_ * DH;
  const bf16* Vp = Vt + (size_t)bh * DH * T_;
  const bf16* Qbase = Q + (size_t)bh * T_ * DH;
  const int b = bh >> 4, h = bh & 15;

#pragma unroll
  for (int phase = 0; phase < 2; ++phase) {
    const int qt = phase ? (31 - qp) : qp;
    const int q0 = qt * 64;
    const int ntiles = 2 * (qt + 1);
    const bf16* Qp = Qbase + (size_t)q0 * DH;

    // Q B-frags for all 64 q of this tile: lane n=l16 -> q, k = kk*32+quad*8+j
    short8 qf[4][2];
#pragma unroll
    for (int qi = 0; qi < 4; ++qi)
#pragma unroll
      for (int kk = 0; kk < 2; ++kk)
        qf[qi][kk] = *(const short8*)(Qp + (size_t)(qi * 16 + l16) * DH + kk * 32 + quad * 8);

    floatx4 Oa[4][4];
    float l_r[4];
#pragma unroll
    for (int qi = 0; qi < 4; ++qi) {
#pragma unroll
      for (int td = 0; td < 4; ++td) Oa[qi][td] = (floatx4){0.f, 0.f, 0.f, 0.f};
      l_r[qi] = 0.f;
    }

    // prime: this wave's first tile into buf 0
    if (wave < ntiles) {
#pragma unroll
      for (int i = 0; i < 4; ++i) {
        int t = lane + i * 64;
        int rk = t >> 3, ck = (t & 7) ^ (rk & 7);
        async_cp16(&tiles[wave][0][t * 8], Kp + (size_t)(wave * 32 + rk) * DH + ck * 8);
        int rv = t >> 2, cv = (t & 3) ^ (rv & 3);
        async_cp16(&tiles[wave][0][2048 + t * 8], Vp + (size_t)rv * T_ + wave * 32 + cv * 8);
      }
    }

    int buf = 0;
    for (int kt2 = wave; kt2 < ntiles; kt2 += 4, buf ^= 1) {
      const bf16* Ks = &tiles[wave][buf][0];
      const bf16* Vs = &tiles[wave][buf][2048];

      wave_wait_dma();
      short8 kf[2][2], vf[4];
#pragma unroll
      for (int kk = 0; kk < 2; ++kk)
#pragma unroll
        for (int tj = 0; tj < 2; ++tj) {
          int r = tj * 16 + l16;
          int cg = kk * 4 + quad;
          kf[kk][tj] = *(const short8*)(Ks + (r * 8 + (cg ^ (r & 7))) * 8);
        }
#pragma unroll
      for (int td = 0; td < 4; ++td) {
        int r = td * 16 + l16;
        vf[td] = *(const short8*)(Vs + (r * 4 + (quad ^ (r & 3))) * 8);
      }

      // prefetch this wave's next tile (kt2+4) into the other buffer
      if (kt2 + 4 < ntiles) {
#pragma unroll
        for (int i = 0; i < 4; ++i) {
          int t = lane + i * 64;
          int rk = t >> 3, ck = (t & 7) ^ (rk & 7);
          async_cp16(&tiles[wave][buf ^ 1][t * 8],
                     Kp + (size_t)((kt2 + 4) * 32 + rk) * DH + ck * 8);
          int rv = t >> 2, cv = (t & 3) ^ (rv & 3);
          async_cp16(&tiles[wave][buf ^ 1][2048 + t * 8],
                     Vp + (size_t)rv * T_ + (kt2 + 4) * 32 + cv * 8);
        }
      }

      // S^T[key][q]: C layout row=key=quad*4+reg (+16*tj), col=q=l16
      floatx4 S[4][2];
#pragma unroll
      for (int qi = 0; qi < 4; ++qi)
#pragma unroll
        for (int tj = 0; tj < 2; ++tj) S[qi][tj] = (floatx4){0.f, 0.f, 0.f, 0.f};
#pragma unroll
      for (int kk = 0; kk < 2; ++kk)
#pragma unroll
        for (int tj = 0; tj < 2; ++tj)
#pragma unroll
          for (int qi = 0; qi < 4; ++qi)
            S[qi][tj] = __builtin_amdgcn_mfma_f32_16x16x32_bf16(kf[kk][tj], qf[qi][kk],
                                                                S[qi][tj], 0, 0, 0);

      if (kt2 >= 2 * qt) {  // diagonal tiles: causal mask (key > q)
#pragma unroll
        for (int qi = 0; qi < 4; ++qi) {
          const int q = q0 + qi * 16 + l16;
#pragma unroll
          for (int tj = 0; tj < 2; ++tj)
#pragma unroll
            for (int r = 0; r < 4; ++r) {
              int key = kt2 * 32 + tj * 16 + quad * 4 + r;
              if (key > q) S[qi][tj][r] = -3.0e38f;
            }
        }
      }

      // no-max softmax: exp2 (scale*log2e folded into Q), per-lane partial l
      unsigned lo[4][2], hi[4][2];
#pragma unroll
      for (int qi = 0; qi < 4; ++qi) {
#pragma unroll
        for (int tj = 0; tj < 2; ++tj)
#pragma unroll
          for (int r = 0; r < 4; ++r)
            S[qi][tj][r] = __builtin_amdgcn_exp2f(S[qi][tj][r]);
        l_r[qi] += ((S[qi][0][0] + S[qi][0][1]) + (S[qi][0][2] + S[qi][0][3])) +
                   ((S[qi][1][0] + S[qi][1][1]) + (S[qi][1][2] + S[qi][1][3]));
#pragma unroll
        for (int tj = 0; tj < 2; ++tj) {
          lo[qi][tj] = pack2(S[qi][tj][0], S[qi][tj][1]);
          hi[qi][tj] = pack2(S[qi][tj][2], S[qi][tj][3]);
        }
      }

      // P^T B-frag (32 keys) via quad permute [verified R2/R3/R5], then PV
      const int sl0 = l16 + ((lane & 16) << 1);
      const int sl1 = sl0 + 16;
      const bool sel = (quad >> 1) != 0;
#pragma unroll
      for (int qi = 0; qi < 4; ++qi) {
        unsigned a0 = __shfl((int)lo[qi][0], sl0), b0 = __shfl((int)lo[qi][1], sl0);
        unsigned a1 = __shfl((int)hi[qi][0], sl0), b1 = __shfl((int)hi[qi][1], sl0);
        unsigned a2 = __shfl((int)lo[qi][0], sl1), b2 = __shfl((int)lo[qi][1], sl1);
        unsigned a3 = __shfl((int)hi[qi][0], sl1), b3 = __shfl((int)hi[qi][1], sl1);
        union { unsigned u[4]; short8 v; } pfu;
        pfu.u[0] = sel ? b0 : a0;
        pfu.u[1] = sel ? b1 : a1;
        pfu.u[2] = sel ? b2 : a2;
        pfu.u[3] = sel ? b3 : a3;
#pragma unroll
        for (int td = 0; td < 4; ++td)
          Oa[qi][td] = __builtin_amdgcn_mfma_f32_16x16x32_bf16(vf[td], pfu.v, Oa[qi][td], 0, 0, 0);
      }
    }

    // wave-level l: sum across quads
#pragma unroll
    for (int qi = 0; qi < 4; ++qi) {
      l_r[qi] += __shfl_xor(l_r[qi], 16);
      l_r[qi] += __shfl_xor(l_r[qi], 32);
    }

    // publish partials into own (dead, drained) tile region; lane-linear.
    float* cb = (float*)&tiles[wave][0][0];
#pragma unroll
    for (int qi = 0; qi < 4; ++qi) {
#pragma unroll
      for (int td = 0; td < 4; ++td)
        ((floatx4*)cb)[(qi * 4 + td) * 64 + lane] = Oa[qi][td];
      if (quad == 0) lx[wave][qi * 16 + l16] = l_r[qi];
    }
    __syncthreads();

    // combine: wave handles q-rows qi==wave across all 4 source regions
    {
      const float lsum = lx[0][wave * 16 + l16] + lx[1][wave * 16 + l16] +
                         lx[2][wave * 16 + l16] + lx[3][wave * 16 + l16];
      const float rl = __builtin_amdgcn_rcpf(lsum);
      bf16* op = Og + ((size_t)(b * T_ + q0 + wave * 16 + l16)) * DM + h * DH + quad * 4;
#pragma unroll
      for (int td = 0; td < 4; ++td) {
        floatx4 s = (floatx4){0.f, 0.f, 0.f, 0.f};
#pragma unroll
        for (int src = 0; src < 4; ++src) {
          floatx4 p = ((const floatx4*)&tiles[src][0][0])[(wave * 4 + td) * 64 + lane];
          s[0] += p[0]; s[1] += p[1]; s[2] += p[2]; s[3] += p[3];
        }
        bf4 o;
        o.x = __float2bfloat16(s[0] * rl);
        o.y = __float2bfloat16(s[1] * rl);
        o.z = __float2bfloat16(s[2] * rl);
        o.w = __float2bfloat16(s[3] * rl);
        *(bf4*)(op + td * 16) = o;
      }
    }
    if (phase == 0) __syncthreads();  // regions reused as tiles in phase 1
  }
}

// ---------------------------------------------------------------- launch
extern "C" void kernel_launch(void* const* d_in, const int* in_sizes, int n_in,
                              void* d_out, int out_size, void* d_ws, size_t ws_size,
                              hipStream_t stream) {
  (void)in_sizes; (void)n_in; (void)out_size; (void)ws_size;
  const float* query = (const float*)d_in[0];
  const float* key_  = (const float*)d_in[1];
  const float* value = (const float*)d_in[2];
  const float* q_w = (const float*)d_in[3];
  const float* q_b = (const float*)d_in[4];
  const float* k_w = (const float*)d_in[5];
  const float* k_b = (const float*)d_in[6];
  const float* v_w = (const float*)d_in[7];
  const float* v_b = (const float*)d_in[8];
  const float* o_w = (const float*)d_in[9];
  const float* o_b = (const float*)d_in[10];

  char* ws = (char*)d_ws;
  const size_t MB = (size_t)1 << 20;
  bf16* Xq = (bf16*)(ws + 0 * MB);
  bf16* Xk = (bf16*)(ws + 8 * MB);
  bf16* Xv = (bf16*)(ws + 16 * MB);
  bf16* Wq = (bf16*)(ws + 24 * MB);
  bf16* Wk = (bf16*)(ws + 26 * MB);
  bf16* Wv = (bf16*)(ws + 28 * MB);
  bf16* Wo = (bf16*)(ws + 30 * MB);
  bf16* Qb = (bf16*)(ws + 32 * MB);  // [B,H,T,dh]
  bf16* Kb = (bf16*)(ws + 40 * MB);  // [B,H,T,dh]
  bf16* Vt = (bf16*)(ws + 48 * MB);  // [B,H,dh,T]
  bf16* An = (bf16*)(ws + 64 * MB);  // [B,T,D]

  CvtArgs ca;
  ca.src[0] = query; ca.src[1] = key_; ca.src[2] = value;
  ca.src[3] = q_w; ca.src[4] = k_w; ca.src[5] = v_w; ca.src[6] = o_w;
  ca.dst[0] = Xq; ca.dst[1] = Xk; ca.dst[2] = Xv;
  ca.dst[3] = Wq; ca.dst[4] = Wk; ca.dst[5] = Wv; ca.dst[6] = Wo;
  cvt_kernel<<<2048, 256, 0, stream>>>(ca);

  GemmBatch gb;
  gb.A[0] = Xq; gb.A[1] = Xk; gb.A[2] = Xv;
  gb.W[0] = Wq; gb.W[1] = Wk; gb.W[2] = Wv;
  gb.bias[0] = q_b; gb.bias[1] = k_b; gb.bias[2] = v_b;
  gb.out[0] = Qb; gb.out[1] = Kb; gb.out[2] = Vt;
  gb.scale[0] = 0.125f * LOG2E; gb.scale[1] = 1.f; gb.scale[2] = 1.f;
  gb.vmode[0] = 0; gb.vmode[1] = 0; gb.vmode[2] = 1;
  qkv_gemm<<<768, 256, 0, stream>>>(gb);

  attn_kernel<<<512, 256, 0, stream>>>(Qb, Kb, Vt, An);
  out_gemm<<<512, 256, 0, stream>>>(An, Wo, o_b, (float*)d_out);
}